// Round 1
// baseline (99.969 us; speedup 1.0000x reference)
//
#include <hip/hip_runtime.h>
#include <math.h>

#define BSZ 512      // batch
#define FDIM 512     // features
#define NK 32        // num_kernels
#define DD 16        // dim_per_kernel
#define NDIM (NK*DD) // 512
#define OUTW (FDIM + NK)  // 544

// ---------------------------------------------------------------------------
// Kernel 1: m = x @ T (fp32 VALU GEMM).
//   grid 256 = (128 row-groups of 4) x (2 col-halves), 256 threads.
//   Each thread computes one output column n for 4 rows (x rows are
//   block-uniform -> compiler scalarizes to s_load; T reads are coalesced).
//   Writes m[B][512] row-major AND mT[512][B] (thread's 4-row column is a
//   contiguous float4 of mT -> free transpose). Also copies x -> out and
//   zeroes the feats columns (out is re-poisoned before every launch).
// ---------------------------------------------------------------------------
__global__ __launch_bounds__(256) void k_gemm_prep(
    const float* __restrict__ x, const float* __restrict__ T,
    float* __restrict__ m, float* __restrict__ mT, float* __restrict__ out) {
  const int tid = threadIdx.x;
  const int ig  = blockIdx.x >> 1;   // row group 0..127
  const int nh  = blockIdx.x & 1;    // col half
  const int i0  = ig * 4;
  const int n   = nh * 256 + tid;    // this thread's output column

  float acc[4];
#pragma unroll
  for (int r = 0; r < 4; ++r) acc[r] = 0.f;

#pragma unroll 4
  for (int fb = 0; fb < FDIM / 4; ++fb) {
    // x fragments: block-uniform addresses (scalar loads)
    float4 xv[4];
#pragma unroll
    for (int r = 0; r < 4; ++r)
      xv[r] = *(const float4*)(x + (i0 + r) * FDIM + fb * 4);
    // T fragments: coalesced per-lane
    const float t0 = T[(fb * 4 + 0) * NDIM + n];
    const float t1 = T[(fb * 4 + 1) * NDIM + n];
    const float t2 = T[(fb * 4 + 2) * NDIM + n];
    const float t3 = T[(fb * 4 + 3) * NDIM + n];
#pragma unroll
    for (int r = 0; r < 4; ++r) {
      acc[r] = fmaf(xv[r].x, t0, acc[r]);
      acc[r] = fmaf(xv[r].y, t1, acc[r]);
      acc[r] = fmaf(xv[r].z, t2, acc[r]);
      acc[r] = fmaf(xv[r].w, t3, acc[r]);
    }
  }

  // m row-major (coalesced)
#pragma unroll
  for (int r = 0; r < 4; ++r) m[(i0 + r) * NDIM + n] = acc[r];
  // mT: thread's column is contiguous float4 at mT[n][i0..i0+3]
  *(float4*)(mT + (size_t)n * BSZ + i0) =
      make_float4(acc[0], acc[1], acc[2], acc[3]);

  // Output prep: copy x (nh==0 blocks) / zero feats (nh==1 blocks)
  if (nh == 0) {
    const int row = i0 + (tid >> 6);
    const int c4  = (tid & 63);
    *(float4*)(out + (size_t)row * OUTW + c4 * 4) =
        *(const float4*)(x + (size_t)row * FDIM + c4 * 4);
    *(float4*)(out + (size_t)row * OUTW + (c4 + 64) * 4) =
        *(const float4*)(x + (size_t)row * FDIM + (c4 + 64) * 4);
  } else {
    if (tid < 128) {
      const int row = i0 + (tid >> 5);
      const int kc  = tid & 31;
      out[(size_t)row * OUTW + FDIM + kc] = 0.f;
    }
  }
}

// ---------------------------------------------------------------------------
// Kernel 2: feats[i,k] = sum_j exp(-sum_d |m[i,k,d]-m[j,k,d]|)
//   grid 256 = (128 i-groups of 4) x (2 j-halves), 1024 threads (16 waves).
//   wave wv handles k in {2wv, 2wv+1}; lane handles j = jh*256+lane+{0,64,128,192}.
//   A-fragment (4 i x 16 d floats) loaded once per k as float4 broadcasts,
//   reused across 4 j per lane. |a-v| pairs compile to sub + add-with-abs
//   modifier (2 VALU/element). Wave shuffle-reduce -> 2 atomicAdds/output.
// ---------------------------------------------------------------------------
__global__ __launch_bounds__(1024) void k_dist(
    const float* __restrict__ m, const float* __restrict__ mT,
    float* __restrict__ out) {
  const int tid  = threadIdx.x;
  const int ig   = blockIdx.x >> 1;
  const int jh   = blockIdx.x & 1;
  const int i0   = ig * 4;
  const int lane = tid & 63;
  const int wv   = __builtin_amdgcn_readfirstlane(tid >> 6);  // wave id 0..15
  const int jb   = jh * 256 + lane;

#pragma unroll
  for (int kl = 0; kl < 2; ++kl) {
    const int k = wv * 2 + kl;  // uniform

    // A fragment: a[ii][d] = m[i0+ii][k*16+d] (broadcast loads, L1-hot)
    float a[4][DD];
#pragma unroll
    for (int ii = 0; ii < 4; ++ii) {
      float4* ap = (float4*)&a[ii][0];
#pragma unroll
      for (int q = 0; q < 4; ++q)
        ap[q] = *(const float4*)(m + (i0 + ii) * NDIM + k * DD + 4 * q);
    }

    float dist[4][4];
#pragma unroll
    for (int ii = 0; ii < 4; ++ii)
#pragma unroll
      for (int nj = 0; nj < 4; ++nj) dist[ii][nj] = 0.f;

#pragma unroll
    for (int d = 0; d < DD; ++d) {
      const float* vr = mT + (size_t)(k * DD + d) * BSZ + jb;
      const float v0 = vr[0];
      const float v1 = vr[64];
      const float v2 = vr[128];
      const float v3 = vr[192];
#pragma unroll
      for (int ii = 0; ii < 4; ++ii) {
        const float av = a[ii][d];
        dist[ii][0] += fabsf(av - v0);
        dist[ii][1] += fabsf(av - v1);
        dist[ii][2] += fabsf(av - v2);
        dist[ii][3] += fabsf(av - v3);
      }
    }

#pragma unroll
    for (int ii = 0; ii < 4; ++ii) {
      float s = __expf(-dist[ii][0]) + __expf(-dist[ii][1]) +
                __expf(-dist[ii][2]) + __expf(-dist[ii][3]);
      // wave-wide sum (64 lanes)
#pragma unroll
      for (int off = 32; off >= 1; off >>= 1) s += __shfl_xor(s, off);
      if (lane == 0)
        atomicAdd(out + (size_t)(i0 + ii) * OUTW + FDIM + k, s);
    }
  }
}

extern "C" void kernel_launch(void* const* d_in, const int* in_sizes, int n_in,
                              void* d_out, int out_size, void* d_ws,
                              size_t ws_size, hipStream_t stream) {
  (void)in_sizes; (void)n_in; (void)out_size; (void)ws_size;
  const float* x = (const float*)d_in[0];
  const float* T = (const float*)d_in[1];
  float* out = (float*)d_out;
  float* m  = (float*)d_ws;              // [512][512] fp32, 1 MB
  float* mT = m + (size_t)BSZ * NDIM;    // [512][512] fp32, 1 MB

  hipLaunchKernelGGL(k_gemm_prep, dim3(256), dim3(256), 0, stream, x, T, m, mT, out);
  hipLaunchKernelGGL(k_dist, dim3(256), dim3(1024), 0, stream, m, mT, out);
}

// Round 2
// 95.085 us; speedup vs baseline: 1.0514x; 1.0514x over previous
//
#include <hip/hip_runtime.h>
#include <math.h>

#define BSZ 512      // batch
#define FDIM 512     // features
#define NK 32        // num_kernels
#define DD 16        // dim_per_kernel
#define NDIM (NK*DD) // 512
#define OUTW (FDIM + NK)  // 544

// ---------------------------------------------------------------------------
// Kernel 1: m = x @ T (fp32 VALU), row-major m only. Plus output prep
// (copy x into out[:, :512], zero out[:, 512:544]).
//   grid 256 = (128 row-groups of 4) x (2 col-halves), 512 threads (8 waves).
//   1 block/CU, 8 waves/CU across ALL 256 CUs (old version idled half the
//   chip). Thread = 1 row x 2 cols: float2 T loads (coalesced, 512B/wave),
//   x row is wave-uniform -> scalar s_load on the SMEM pipe.
//   T L2 traffic: 256 blocks x 512KB = 128 MB ~= 3.7us at L2 speed.
// ---------------------------------------------------------------------------
__global__ __launch_bounds__(512) void k_gemm(
    const float* __restrict__ x, const float* __restrict__ T,
    float* __restrict__ m, float* __restrict__ out) {
  const int t  = threadIdx.x;
  const int b  = blockIdx.x;
  const int ig = b >> 1;                 // row group 0..127
  const int ch = b & 1;                  // col half
  // rl uniform per wave (t>>7 constant across a 64-lane wave) — force scalar
  const int rl = __builtin_amdgcn_readfirstlane(t >> 7);  // 0..3
  const int cp = t & 127;                // col-pair within half
  const int row = ig * 4 + rl;
  const int c   = ch * 256 + cp * 2;

  const float* __restrict__ xr = x + (size_t)row * FDIM;
  float a0 = 0.f, a1 = 0.f;
#pragma unroll 16
  for (int k = 0; k < FDIM; ++k) {
    const float xv = xr[k];                                  // s_load (uniform)
    const float2 tv = *(const float2*)(T + (size_t)k * NDIM + c);
    a0 = fmaf(xv, tv.x, a0);
    a1 = fmaf(xv, tv.y, a1);
  }
  *(float2*)(m + (size_t)row * NDIM + c) = make_float2(a0, a1);

  // ---- output prep: g in [0, 131072) over the whole grid ----
  const int g = b * 512 + t;
  if (g < 65536) {
    // copy x -> out[:, :512] as float4s: 512 rows x 128 float4
    const int orow = g >> 7, c4 = g & 127;
    *(float4*)(out + (size_t)orow * OUTW + c4 * 4) =
        *(const float4*)(x + (size_t)orow * FDIM + c4 * 4);
  } else if (g < 65536 + 16384) {
    // zero feats columns (out is poisoned 0xAA before every launch)
    const int idx = g - 65536;
    const int orow = idx >> 5, kk = idx & 31;
    out[(size_t)orow * OUTW + FDIM + kk] = 0.f;
  }
}

// ---------------------------------------------------------------------------
// Kernel 2: feats[i,k] += sum_j exp(-sum_d |m[i,k,d]-m[j,k,d]|)
//   Lane <-> i (64 i's per wave) so the j-side read m[j][16k..16k+16) is
//   WAVE-UNIFORM -> compiler emits s_load_dwordx4 on the scalar pipe; the
//   vector-memory pipe is idle in the hot loop. Per-lane A fragment
//   m[i][16k..+16) is one aligned 64B line per lane, loaded once.
//   grid 1024 = (8 i-groups of 64) x 32 k x 4 j-quarters, 256 thr (4 waves).
//   wave w handles j in [jq*128 + w*32, +32). 16 waves/CU.
//   Per j: 16x(sub + abs-add) = 32 VALU + 1 exp. VALU floor ~3.4us.
//   LDS-reduce 4 waves -> atomicAdd (4 j-quarter blocks contend per addr;
//   k_gemm zero-inits the feats columns).
// ---------------------------------------------------------------------------
__global__ __launch_bounds__(256) void k_dist(
    const float* __restrict__ m, float* __restrict__ out) {
  const int t   = threadIdx.x;
  const int bid = blockIdx.x;
  const int ig  = bid >> 7;        // 0..7
  const int k   = (bid >> 2) & 31; // 0..31
  const int jq  = bid & 3;         // j quarter
  const int lane = t & 63;
  const int w    = __builtin_amdgcn_readfirstlane(t >> 6);  // wave 0..3
  const int i    = ig * 64 + lane;

  // A fragment (per-lane): m[i][16k .. 16k+16), one 64B line per lane
  float a[DD];
  {
    const float4* ap = (const float4*)(m + (size_t)i * NDIM + k * DD);
    float4 a0 = ap[0], a1 = ap[1], a2 = ap[2], a3 = ap[3];
    a[0]=a0.x; a[1]=a0.y; a[2]=a0.z;  a[3]=a0.w;
    a[4]=a1.x; a[5]=a1.y; a[6]=a1.z;  a[7]=a1.w;
    a[8]=a2.x; a[9]=a2.y; a[10]=a2.z; a[11]=a2.w;
    a[12]=a3.x;a[13]=a3.y;a[14]=a3.z; a[15]=a3.w;
  }

  const int jbase = jq * 128 + w * 32;
  const float* __restrict__ bb = m + (size_t)jbase * NDIM + k * DD;

  float f = 0.f;
  // current-j registers (uniform -> SGPRs); prefetch j+1 each iteration.
  // j=31 prefetch reads "row 512" = 64B past m, still inside d_ws: harmless.
  float4 c0 = ((const float4*)bb)[0];
  float4 c1 = ((const float4*)bb)[1];
  float4 c2 = ((const float4*)bb)[2];
  float4 c3 = ((const float4*)bb)[3];
#pragma unroll 4
  for (int j = 0; j < 32; ++j) {
    const float4* nb = (const float4*)(bb + (size_t)(j + 1) * NDIM);
    float4 n0 = nb[0], n1 = nb[1], n2 = nb[2], n3 = nb[3];
    float d =
        fabsf(a[0]  - c0.x) + fabsf(a[1]  - c0.y) +
        fabsf(a[2]  - c0.z) + fabsf(a[3]  - c0.w) +
        fabsf(a[4]  - c1.x) + fabsf(a[5]  - c1.y) +
        fabsf(a[6]  - c1.z) + fabsf(a[7]  - c1.w) +
        fabsf(a[8]  - c2.x) + fabsf(a[9]  - c2.y) +
        fabsf(a[10] - c2.z) + fabsf(a[11] - c2.w) +
        fabsf(a[12] - c3.x) + fabsf(a[13] - c3.y) +
        fabsf(a[14] - c3.z) + fabsf(a[15] - c3.w);
    f += __expf(-d);
    c0 = n0; c1 = n1; c2 = n2; c3 = n3;
  }

  // reduce the 4 waves' partials, one atomic per (i,k) per block
  __shared__ float lds[256];
  lds[t] = f;
  __syncthreads();
  if (t < 64) {
    const float s = lds[t] + lds[t + 64] + lds[t + 128] + lds[t + 192];
    atomicAdd(out + (size_t)(ig * 64 + t) * OUTW + FDIM + k, s);
  }
}

extern "C" void kernel_launch(void* const* d_in, const int* in_sizes, int n_in,
                              void* d_out, int out_size, void* d_ws,
                              size_t ws_size, hipStream_t stream) {
  (void)in_sizes; (void)n_in; (void)out_size; (void)ws_size;
  const float* x = (const float*)d_in[0];
  const float* T = (const float*)d_in[1];
  float* out = (float*)d_out;
  float* m   = (float*)d_ws;  // [512][512] fp32, 1 MB (+64B prefetch slack)

  hipLaunchKernelGGL(k_gemm, dim3(256), dim3(512), 0, stream, x, T, m, out);
  hipLaunchKernelGGL(k_dist, dim3(1024), dim3(256), 0, stream, m, out);
}